// Round 7
// baseline (398.178 us; speedup 1.0000x reference)
//
#include <hip/hip_runtime.h>
#include <hip/hip_bf16.h>
#include <stdint.h>

typedef unsigned short u16;
typedef __bf16 bf16_t;
typedef bf16_t bf16x8 __attribute__((ext_vector_type(8)));
typedef float f32x4 __attribute__((ext_vector_type(4)));

__device__ __forceinline__ u16 f2b(float f) {
    union { float f; uint32_t i; } v; v.f = f;
    uint32_t r = v.i + 0x7FFFu + ((v.i >> 16) & 1u);
    return (u16)(r >> 16);
}
__device__ __forceinline__ uint32_t pk2(float a, float b) {
    __hip_bfloat162 h = __float22bfloat162_rn(float2{a, b});
    return *(const uint32_t*)&h;
}
__device__ __forceinline__ uint4 pack8(float4 lo, float4 hi) {
    uint4 r;
    r.x = pk2(lo.x, lo.y); r.y = pk2(lo.z, lo.w);
    r.z = pk2(hi.x, hi.y); r.w = pk2(hi.z, hi.w);
    return r;
}
// async global->LDS DMA, 16B per lane (m97 idiom: LDS dst linear in lane)
__device__ __forceinline__ void async16(const u16* g, u16* l) {
    __builtin_amdgcn_global_load_lds(
        (const __attribute__((address_space(1))) uint32_t*)g,
        (__attribute__((address_space(3))) uint32_t*)l,
        16, 0, 0);
}

// ---------------- GEMM core: C[M,N] = X[M,1024] @ W[1024,N] + bias ----------------
// WT = W^T bf16 [N][K]. 128x128 tile, BK=64, 2x2 wave quadrants, 4x4 16x16x32 frags.
// LDS tiles 128x64, unpadded, XOR-swizzled: physical 16B-block pb of row r holds
// logical block pb^(r&7) -> frag b128 reads are 2-way (free). B staged via async16
// (zero VGPRs); A staged via transient f32->bf16 VGPR pass when XF32 (qkv fallback)
// or async16 when bf16. No registers held across the compute phase (R5 spill fix).
// mode 0: bf16 scatter [B,H,S,D]; mode 1: f32 row-major; mode 2: bf16 V^T [BH,64,2048]
template<bool XF32>
__device__ __forceinline__ void gemm128(const void* __restrict__ Xv,
                                        const u16* __restrict__ WT,
                                        const float* __restrict__ bias,
                                        u16* __restrict__ dstb,
                                        float* __restrict__ dstf, int mode)
{
    __shared__ __align__(16) u16 As[128 * 64];
    __shared__ __align__(16) u16 Bs[128 * 64];
    const int t    = threadIdx.x;
    const int lane = t & 63;
    const int quad = lane >> 4;
    const int l15  = lane & 15;
    const int m0 = blockIdx.y * 128;
    const int n0 = blockIdx.x * 128;
    const int wave = t >> 6;
    const int wm = (wave >> 1) * 64;
    const int wn = (wave & 1) * 64;

    f32x4 acc[4][4];
#pragma unroll
    for (int i = 0; i < 4; i++)
#pragma unroll
        for (int j = 0; j < 4; j++)
#pragma unroll
            for (int r = 0; r < 4; r++) acc[i][j][r] = 0.0f;

    // staging chunk map: ci = c*256+t; row r=ci>>3, physical block pb=ci&7,
    // logical (global) block lb = pb ^ (r&7)
    int rr[4], lb[4];
#pragma unroll
    for (int c = 0; c < 4; c++) {
        const int ci = c * 256 + t;
        rr[c] = ci >> 3;
        lb[c] = (ci & 7) ^ (rr[c] & 7);
    }

    for (int kt = 0; kt < 1024; kt += 64) {
        __syncthreads();                    // (a) prior tile's frag reads complete
#pragma unroll
        for (int c = 0; c < 4; c++)         // B: async DMA, no VGPRs
            async16(WT + (n0 + rr[c]) * 1024 + kt + lb[c] * 8, &Bs[(c * 256 + t) * 8]);
        if (XF32) {                         // A: f32 load -> bf16 pack -> LDS
#pragma unroll
            for (int c = 0; c < 4; c++) {
                const float* g = (const float*)Xv + (m0 + rr[c]) * 1024 + kt + lb[c] * 8;
                const float4 lo = *(const float4*)g;
                const float4 hi = *(const float4*)(g + 4);
                *(uint4*)&As[(c * 256 + t) * 8] = pack8(lo, hi);
            }
        } else {                            // A: async DMA (R9: bf16 prepass path)
#pragma unroll
            for (int c = 0; c < 4; c++)
                async16((const u16*)Xv + (m0 + rr[c]) * 1024 + kt + lb[c] * 8,
                        &As[(c * 256 + t) * 8]);
        }
        __syncthreads();                    // (b) vmcnt drained + staging visible

#pragma unroll
        for (int kk = 0; kk < 64; kk += 32) {
            bf16x8 af[4], bfv[4];
#pragma unroll
            for (int i = 0; i < 4; i++) {
                const int ra = wm + i * 16 + l15;
                const int rb2 = wn + i * 16 + l15;
                af[i]  = *(const bf16x8*)&As[ra * 64 + (((kk >> 3) + quad) ^ (l15 & 7)) * 8];
                bfv[i] = *(const bf16x8*)&Bs[rb2 * 64 + (((kk >> 3) + quad) ^ (l15 & 7)) * 8];
            }
#pragma unroll
            for (int i = 0; i < 4; i++)
#pragma unroll
                for (int j = 0; j < 4; j++)
                    acc[i][j] = __builtin_amdgcn_mfma_f32_16x16x32_bf16(af[i], bfv[j], acc[i][j], 0, 0, 0);
        }
    }

    // epilogue: C row = quad*4 + r, col = lane&15 (HW-verified R4)
#pragma unroll
    for (int i = 0; i < 4; i++) {
        const int rb = m0 + wm + i * 16 + quad * 4;
#pragma unroll
        for (int j = 0; j < 4; j++) {
            const int col = n0 + wn + j * 16 + l15;
            const float bias_v = bias[col];
            if (mode == 2) {
                // V^T direct store: 4 consecutive s at fixed (h,d) -> packed b64
                const int b = rb >> 11, s = rb & 2047;
                const int h = col >> 6, d = col & 63;
                uint2 pk;
                pk.x = pk2(acc[i][j][0] + bias_v, acc[i][j][1] + bias_v);
                pk.y = pk2(acc[i][j][2] + bias_v, acc[i][j][3] + bias_v);
                *(uint2*)&dstb[((b * 16 + h) * 64 + d) * 2048 + s] = pk;
            } else {
#pragma unroll
                for (int r = 0; r < 4; r++) {
                    const float v = acc[i][j][r] + bias_v;
                    const int gm = rb + r;
                    if (mode == 0) {
                        const int b = gm >> 11, s = gm & 2047;
                        const int h = col >> 6, d = col & 63;
                        dstb[((b * 16 + h) * 2048 + s) * 64 + d] = f2b(v);
                    } else {
                        dstf[gm * 1024 + col] = v;
                    }
                }
            }
        }
    }
}

// R9: f32 -> bf16 convert prepass (memory-bound, ~150 MB total traffic).
__global__ __launch_bounds__(256)
void convert_x(const float* __restrict__ q_in, const float* __restrict__ k_in,
               const float* __restrict__ v_in, u16* __restrict__ Xb)
{
    const int z = blockIdx.y;
    const float* src = (z == 0) ? q_in : (z == 1) ? k_in : v_in;
    u16* dst = Xb + z * (8 * 1024 * 1024);
    const int i = (blockIdx.x * 256 + threadIdx.x) * 8;
    const float4 lo = *(const float4*)(src + i);
    const float4 hi = *(const float4*)(src + i + 4);
    *(uint4*)(dst + i) = pack8(lo, hi);
}

__global__ __launch_bounds__(256)
void qkv_kernel_f32(const float* __restrict__ q_in, const float* __restrict__ k_in,
                    const float* __restrict__ v_in, const u16* __restrict__ WT,
                    const float* __restrict__ bq, const float* __restrict__ bk,
                    const float* __restrict__ bv,
                    u16* __restrict__ Qo, u16* __restrict__ Ko, u16* __restrict__ VTo)
{
    const int z = blockIdx.z;
    const float* X   = (z == 0) ? q_in : (z == 1) ? k_in : v_in;
    const u16* wt    = WT + ((z == 0) ? 2 : (z == 1) ? 1 : 0) * (1024 * 1024);
    const float* bias= (z == 0) ? bq : (z == 1) ? bk : bv;
    u16* dst         = (z == 0) ? Qo : (z == 1) ? Ko : VTo;
    gemm128<true>(X, wt, bias, dst, nullptr, (z == 2) ? 2 : 0);
}

// R9: all-async16 qkv reading pre-converted bf16 X
__global__ __launch_bounds__(256)
void qkv_kernel_b16(const u16* __restrict__ Xb, const u16* __restrict__ WT,
                    const float* __restrict__ bq, const float* __restrict__ bk,
                    const float* __restrict__ bv,
                    u16* __restrict__ Qo, u16* __restrict__ Ko, u16* __restrict__ VTo)
{
    const int z = blockIdx.z;
    const u16* X     = Xb + z * (8 * 1024 * 1024);
    const u16* wt    = WT + ((z == 0) ? 2 : (z == 1) ? 1 : 0) * (1024 * 1024);
    const float* bias= (z == 0) ? bq : (z == 1) ? bk : bv;
    u16* dst         = (z == 0) ? Qo : (z == 1) ? Ko : VTo;
    gemm128<false>(X, wt, bias, dst, nullptr, (z == 2) ? 2 : 0);
}

__global__ __launch_bounds__(256)
void oproj_kernel(const u16* __restrict__ AO, const u16* __restrict__ WT,
                  const float* __restrict__ bo, float* __restrict__ out)
{
    gemm128<false>(AO, WT + 3 * 1024 * 1024, bo, nullptr, out, 1);
}

// ---------------- weight transpose+cvt: W[1024 k][1024 n] f32 -> WT[n][k] bf16 ----
__global__ void transpose_w(const float* __restrict__ Wv, const float* __restrict__ Wk,
                            const float* __restrict__ Wq, const float* __restrict__ Wo,
                            u16* __restrict__ WT)
{
    __shared__ u16 tile[64][65];
    const int z = blockIdx.z;
    const float* W = (z == 0) ? Wv : (z == 1) ? Wk : (z == 2) ? Wq : Wo;
    u16* dst = WT + z * 1024 * 1024;
    const int r0 = blockIdx.y * 64, c0 = blockIdx.x * 64;
    const int col = threadIdx.x & 63, rb = threadIdx.x >> 6;
#pragma unroll
    for (int r = rb; r < 64; r += 4) tile[r][col] = f2b(W[(r0 + r) * 1024 + c0 + col]);
    __syncthreads();
#pragma unroll
    for (int r = rb; r < 64; r += 4) dst[(c0 + r) * 1024 + r0 + col] = tile[col][r];
}

// ---------------- flash attention (transposed): Tq=64/block, Tk=128 KV tiles -------
// S^T = K·Q^T -> per-lane online softmax (lane owns one q-row via l15).
// O^T = V^T·P^T (+ ones-row slice accumulating l). All barriers are __syncthreads
// (auto vmcnt/lgkm drain) -- safety comes from ISSUE PLACEMENT, not counted waits.
// R6: Q in 8 VGPRs/lane. R8: bounds fix (spill tripwire: FETCH/WRITE +).
// R11: C-init=-m_st, T13 defer-max THR=8, row-sum via ones-row MFMA.
// R12: schedule rework, 3 barriers -> 2, drains hidden:
//   - Ps un-aliased from Ks (LDS 36.8K -> 52K, still 3 blocks/CU) -> K prefetch legal
//   - K[t+1] issued right after (c) (all Ks[t] reads done), flies ~full iter,
//     long-landed when next (a) auto-drains it.
//   - V[t] issued right after (a), hides under QK^T, drained by (c) (mostly landed).
//   schedule: (a) sync | issue V[t] | QK^T | (c) sync | issue K[t+1] | softmax |
//             P->Ps | lgkm fence | PV
__global__ __launch_bounds__(256, 3)
void attn_kernel(const u16* __restrict__ Q, const u16* __restrict__ K,
                 const u16* __restrict__ VT, u16* __restrict__ AO)
{
    __shared__ __align__(16) u16 Ks[128 * 64];    // K tile (swizzle r&7)
    __shared__ __align__(16) u16 Ps[64 * 128];    // P^T (swizzle r&15, wave-private rows)
    __shared__ __align__(16) u16 Vts[80 * 128];   // rows 0..63: V^T (swizzle r&15);
                                                  // row 64: ones, 65..79: zeros

    const int t    = threadIdx.x;
    const int lane = t & 63;
    const int wave = t >> 6;
    const int quad = lane >> 4;
    const int l15  = lane & 15;
    const int bh = blockIdx.y;
    const int qt = blockIdx.x;

    const u16* Qg = Q + (bh * 2048 + qt * 64) * 64;
    const u16* Kg = K + bh * 2048 * 64;
    const u16* Vg = VT + bh * 64 * 2048;

    // hoisted staging maps: running global src pointers + fixed LDS dests
    const u16* kgp[4];
    const u16* vgp[4];
    u16* kld[4];
    u16* vld[4];
#pragma unroll
    for (int c = 0; c < 4; c++) {
        const int ci = c * 256 + t;
        const int krr = ci >> 3, klb = (ci & 7)  ^ (krr & 7);
        const int vrr = ci >> 4, vlb = (ci & 15) ^ (vrr & 15);
        kgp[c] = Kg + krr * 64 + klb * 8;      // += 128*64 per issue
        vgp[c] = Vg + vrr * 2048 + vlb * 8;    // += 128 per issue
        kld[c] = &Ks[ci * 8];
        vld[c] = &Vts[ci * 8];
    }

    // prologue: issue K[0] now; it lands under Q-load + ones-init below
#pragma unroll
    for (int c = 0; c < 4; c++) {
        async16(kgp[c], kld[c]);
        kgp[c] += 128 * 64;
    }

    // ones/zeros rows for the row-sum MFMA slice (written once; staging never
    // touches rows >= 64)
    {
        const int idx = t * 8;                 // 2048 u16 over 256 threads
        const int row = 64 + (idx >> 7);
        const u16 one = 0x3F80;                // bf16 1.0
        u16 vals[8];
#pragma unroll
        for (int i = 0; i < 8; i++) vals[i] = (row == 64) ? one : (u16)0;
        *(uint4*)&Vts[64 * 128 + idx] = *(uint4*)vals;
    }

    // Q fragments in registers (fold 0.125*log2e -> exp2 domain)
    bf16x8 bqr[2];
    {
        const u16* qrow = Qg + (wave * 16 + l15) * 64 + quad * 8;
#pragma unroll
        for (int c = 0; c < 2; c++) {
            uint4 dv = *(const uint4*)(qrow + c * 32);
            u16 tmp[8];
            *(uint4*)tmp = dv;
            float f[8];
#pragma unroll
            for (int i = 0; i < 8; i++) {
                union { float f; uint32_t u; } x; x.u = ((uint32_t)tmp[i]) << 16;
                f[i] = x.f * 0.18033688f;   // 0.125 * log2e
            }
            uint4 pk;
            pk.x = pk2(f[0], f[1]); pk.y = pk2(f[2], f[3]);
            pk.z = pk2(f[4], f[5]); pk.w = pk2(f[6], f[7]);
            bqr[c] = *(bf16x8*)&pk;
        }
    }

    f32x4 o[5];                                // o[4] = online l (ones-row slice)
#pragma unroll
    for (int dj = 0; dj < 5; dj++)
#pragma unroll
        for (int r = 0; r < 4; r++) o[dj][r] = 0.0f;
    float m_st = 0.0f;                         // T13: defer-max, start at 0

    // QK^T A-frag LDS offsets (u16 units): [kk/32][n]
    int ak_off[2][8];
#pragma unroll
    for (int ki = 0; ki < 2; ki++)
#pragma unroll
        for (int n = 0; n < 8; n++)
            ak_off[ki][n] = (n * 16 + l15) * 64 + (((ki * 4) + quad) ^ (l15 & 7)) * 8;
    // PV offsets: av [ks][dj] (dj 0..4), bp [ks]; P-write offsets pw [n]
    int av_off[4][5], bp_off[4], pw_off[8];
#pragma unroll
    for (int ks = 0; ks < 4; ks++) {
        bp_off[ks] = (wave * 16 + l15) * 128 + ((ks * 4 + quad) ^ l15) * 8;
#pragma unroll
        for (int dj = 0; dj < 5; dj++)
            av_off[ks][dj] = (dj * 16 + l15) * 128 + ((ks * 4 + quad) ^ l15) * 8;
    }
#pragma unroll
    for (int n = 0; n < 8; n++)
        pw_off[n] = (wave * 16 + l15) * 128 + ((2 * n + (quad >> 1)) ^ l15) * 8
                    + (quad & 1) * 4;

    for (int kv = 0; kv < 16; kv++) {
        // (a): drains K[t] (issued a full iter ago -> landed); syncs prev PV reads
        //      of Vts before V[t] staging writes; makes Ks[t] visible to all waves
        __syncthreads();
#pragma unroll
        for (int c = 0; c < 4; c++) {      // V[t]: flies under QK^T
            async16(vgp[c], vld[c]);
            vgp[c] += 128;
        }

        // S^T = K·Q^T, accumulator pre-loaded with -m_st (free S-m subtraction)
        f32x4 s[8];
#pragma unroll
        for (int n = 0; n < 8; n++)
#pragma unroll
            for (int r = 0; r < 4; r++) s[n][r] = -m_st;
#pragma unroll
        for (int ki = 0; ki < 2; ki++) {
            const bf16x8 bq = bqr[ki];
#pragma unroll
            for (int n = 0; n < 8; n++) {
                const bf16x8 ak = *(const bf16x8*)&Ks[ak_off[ki][n]];
                s[n] = __builtin_amdgcn_mfma_f32_16x16x32_bf16(ak, bq, s[n], 0, 0, 0);
            }
        }

        // (c): all waves' Ks[t] reads done (K[t+1] may overwrite after this);
        //      drains V[t] (latency mostly absorbed under QK^T) -> Vts visible
        __syncthreads();
        if (kv < 15) {
#pragma unroll
            for (int c = 0; c < 4; c++) {  // K[t+1]: flies across softmax+PV
                async16(kgp[c], kld[c]);
                kgp[c] += 128 * 64;
            }
        }

        // column max (s domain); rescale ONLY on threshold breach (T13)
        float mxn[8];
#pragma unroll
        for (int n = 0; n < 8; n++)
            mxn[n] = fmaxf(fmaxf(s[n][0], s[n][1]), fmaxf(s[n][2], s[n][3]));
        float mx = fmaxf(fmaxf(fmaxf(mxn[0], mxn[1]), fmaxf(mxn[2], mxn[3])),
                         fmaxf(fmaxf(mxn[4], mxn[5]), fmaxf(mxn[6], mxn[7])));
        mx = fmaxf(mx, __shfl_xor(mx, 16));
        mx = fmaxf(mx, __shfl_xor(mx, 32));
        if (__any(mx > 8.0f)) {                // rare: only when tile max grows >8
            const float dm = fmaxf(mx, 0.0f);  // per-column monotone bump
            const float alpha = exp2f(-dm);
#pragma unroll
            for (int n = 0; n < 8; n++)
#pragma unroll
                for (int r = 0; r < 4; r++) s[n][r] -= dm;
            m_st += dm;
#pragma unroll
            for (int dj = 0; dj < 5; dj++)
#pragma unroll
                for (int r = 0; r < 4; r++) o[dj][r] *= alpha;
        }

        // P = exp2(s) -> packed bf16 -> swizzled Ps (wave-private rows)
#pragma unroll
        for (int n = 0; n < 8; n++) {
            uint2 pk;
            pk.x = pk2(exp2f(s[n][0]), exp2f(s[n][1]));
            pk.y = pk2(exp2f(s[n][2]), exp2f(s[n][3]));
            *(uint2*)&Ps[pw_off[n]] = pk;
        }
        asm volatile("s_waitcnt lgkmcnt(0)" ::: "memory");  // wave-private RAW fence

        // O^T += V^T·P^T  (dj=4 is the ones-row slice: accumulates l into o[4])
#pragma unroll
        for (int ks = 0; ks < 4; ks++) {
            const bf16x8 bp = *(const bf16x8*)&Ps[bp_off[ks]];
#pragma unroll
            for (int dj = 0; dj < 5; dj++) {
                const bf16x8 av = *(const bf16x8*)&Vts[av_off[ks][dj]];
                o[dj] = __builtin_amdgcn_mfma_f32_16x16x32_bf16(av, bp, o[dj], 0, 0, 0);
            }
        }
    }

    // epilogue: l for column q=l15 lives in lane (quad 0, l15), reg 0 of o[4]
    const float lsum = __shfl(o[4][0], l15);
    const int b = bh >> 4, h = bh & 15;
    const int sq = qt * 64 + wave * 16 + l15;
    const float inv = 1.0f / lsum;
#pragma unroll
    for (int dj = 0; dj < 4; dj++) {
        uint2 pk;
        pk.x = pk2(o[dj][0] * inv, o[dj][1] * inv);
        pk.y = pk2(o[dj][2] * inv, o[dj][3] * inv);
        *(uint2*)&AO[(b * 2048 + sq) * 1024 + h * 64 + dj * 16 + quad * 4] = pk;
    }
}

extern "C" void kernel_launch(void* const* d_in, const int* in_sizes, int n_in,
                              void* d_out, int out_size, void* d_ws, size_t ws_size,
                              hipStream_t stream)
{
    (void)in_sizes; (void)n_in; (void)out_size;
    const float* value = (const float*)d_in[0];
    const float* key_  = (const float*)d_in[1];
    const float* query = (const float*)d_in[2];
    const float* Wv = (const float*)d_in[3];
    const float* bv = (const float*)d_in[4];
    const float* Wk = (const float*)d_in[5];
    const float* bk = (const float*)d_in[6];
    const float* Wq = (const float*)d_in[7];
    const float* bq = (const float*)d_in[8];
    const float* Wo = (const float*)d_in[9];
    const float* bo = (const float*)d_in[10];

    u16* ws = (u16*)d_ws;
    u16* WT = ws;                          // 4 x 1M bf16 (order: v,k,q,o)
    u16* Q  = ws + 4 * 1024 * 1024;        // 8M bf16 [B,H,S,D]
    u16* K  = Q + 8 * 1024 * 1024;         // 8M [B,H,S,D]
    u16* VT = K + 8 * 1024 * 1024;         // 8M [B,H,D,S] (written directly by qkv)
    u16* AO = VT + 8 * 1024 * 1024;        // 8M [B*S, E]   (72 MB so far)
    u16* Xb = AO + 8 * 1024 * 1024;        // 3 x 8M bf16 converted inputs (q,k,v)
    const size_t need = (size_t)(4 + 8 + 8 + 8 + 8 + 24) * 1024 * 1024 * sizeof(u16);

    transpose_w<<<dim3(16, 16, 4), dim3(256), 0, stream>>>(Wv, Wk, Wq, Wo, WT);
    if (ws_size >= need) {
        convert_x<<<dim3(4096, 3), dim3(256), 0, stream>>>(query, key_, value, Xb);
        qkv_kernel_b16<<<dim3(8, 64, 3), dim3(256), 0, stream>>>(Xb, WT, bq, bk, bv,
                                                                 Q, K, VT);
    } else {
        qkv_kernel_f32<<<dim3(8, 64, 3), dim3(256), 0, stream>>>(query, key_, value,
                                                                 WT, bq, bk, bv,
                                                                 Q, K, VT);
    }
    attn_kernel<<<dim3(32, 64), dim3(256), 0, stream>>>(Q, K, VT, AO);
    oproj_kernel<<<dim3(8, 64, 1), dim3(256), 0, stream>>>(AO, WT, bo, (float*)d_out);
}

// Round 8
// 380.172 us; speedup vs baseline: 1.0474x; 1.0474x over previous
//
#include <hip/hip_runtime.h>
#include <hip/hip_bf16.h>
#include <stdint.h>

typedef unsigned short u16;
typedef __bf16 bf16_t;
typedef bf16_t bf16x8 __attribute__((ext_vector_type(8)));
typedef float f32x4 __attribute__((ext_vector_type(4)));

__device__ __forceinline__ u16 f2b(float f) {
    union { float f; uint32_t i; } v; v.f = f;
    uint32_t r = v.i + 0x7FFFu + ((v.i >> 16) & 1u);
    return (u16)(r >> 16);
}
__device__ __forceinline__ uint32_t pk2(float a, float b) {
    __hip_bfloat162 h = __float22bfloat162_rn(float2{a, b});
    return *(const uint32_t*)&h;
}
__device__ __forceinline__ uint4 pack8(float4 lo, float4 hi) {
    uint4 r;
    r.x = pk2(lo.x, lo.y); r.y = pk2(lo.z, lo.w);
    r.z = pk2(hi.x, hi.y); r.w = pk2(hi.z, hi.w);
    return r;
}
// async global->LDS DMA, 16B per lane (m97 idiom: LDS dst linear in lane)
__device__ __forceinline__ void async16(const u16* g, u16* l) {
    __builtin_amdgcn_global_load_lds(
        (const __attribute__((address_space(1))) uint32_t*)g,
        (__attribute__((address_space(3))) uint32_t*)l,
        16, 0, 0);
}

// ---------------- GEMM core: C[M,N] = X[M,1024] @ W[1024,N] + bias ----------------
// WT = W^T bf16 [N][K]. 128x128 tile, BK=64, 2x2 wave quadrants, 4x4 16x16x32 frags.
// LDS tiles 128x64, unpadded, XOR-swizzled. B staged via async16; A via async16
// (bf16 path) or f32->bf16 VGPR pass (fallback). m0/n0 passed in (R13: callers
// apply XCD-chunk swizzle).
// mode 0: bf16 scatter [B,H,S,D]; mode 1: f32 row-major; mode 2: bf16 V^T [BH,64,2048]
template<bool XF32>
__device__ __forceinline__ void gemm128(const void* __restrict__ Xv,
                                        const u16* __restrict__ WT,
                                        const float* __restrict__ bias,
                                        u16* __restrict__ dstb,
                                        float* __restrict__ dstf, int mode,
                                        int m0, int n0)
{
    __shared__ __align__(16) u16 As[128 * 64];
    __shared__ __align__(16) u16 Bs[128 * 64];
    const int t    = threadIdx.x;
    const int lane = t & 63;
    const int quad = lane >> 4;
    const int l15  = lane & 15;
    const int wave = t >> 6;
    const int wm = (wave >> 1) * 64;
    const int wn = (wave & 1) * 64;

    f32x4 acc[4][4];
#pragma unroll
    for (int i = 0; i < 4; i++)
#pragma unroll
        for (int j = 0; j < 4; j++)
#pragma unroll
            for (int r = 0; r < 4; r++) acc[i][j][r] = 0.0f;

    // staging chunk map: ci = c*256+t; row r=ci>>3, physical block pb=ci&7,
    // logical (global) block lb = pb ^ (r&7)
    int rr[4], lb[4];
#pragma unroll
    for (int c = 0; c < 4; c++) {
        const int ci = c * 256 + t;
        rr[c] = ci >> 3;
        lb[c] = (ci & 7) ^ (rr[c] & 7);
    }

    for (int kt = 0; kt < 1024; kt += 64) {
        __syncthreads();                    // (a) prior tile's frag reads complete
#pragma unroll
        for (int c = 0; c < 4; c++)         // B: async DMA, no VGPRs
            async16(WT + (n0 + rr[c]) * 1024 + kt + lb[c] * 8, &Bs[(c * 256 + t) * 8]);
        if (XF32) {                         // A: f32 load -> bf16 pack -> LDS
#pragma unroll
            for (int c = 0; c < 4; c++) {
                const float* g = (const float*)Xv + (m0 + rr[c]) * 1024 + kt + lb[c] * 8;
                const float4 lo = *(const float4*)g;
                const float4 hi = *(const float4*)(g + 4);
                *(uint4*)&As[(c * 256 + t) * 8] = pack8(lo, hi);
            }
        } else {                            // A: async DMA (R9: bf16 prepass path)
#pragma unroll
            for (int c = 0; c < 4; c++)
                async16((const u16*)Xv + (m0 + rr[c]) * 1024 + kt + lb[c] * 8,
                        &As[(c * 256 + t) * 8]);
        }
        __syncthreads();                    // (b) vmcnt drained + staging visible

#pragma unroll
        for (int kk = 0; kk < 64; kk += 32) {
            bf16x8 af[4], bfv[4];
#pragma unroll
            for (int i = 0; i < 4; i++) {
                const int ra = wm + i * 16 + l15;
                const int rb2 = wn + i * 16 + l15;
                af[i]  = *(const bf16x8*)&As[ra * 64 + (((kk >> 3) + quad) ^ (l15 & 7)) * 8];
                bfv[i] = *(const bf16x8*)&Bs[rb2 * 64 + (((kk >> 3) + quad) ^ (l15 & 7)) * 8];
            }
#pragma unroll
            for (int i = 0; i < 4; i++)
#pragma unroll
                for (int j = 0; j < 4; j++)
                    acc[i][j] = __builtin_amdgcn_mfma_f32_16x16x32_bf16(af[i], bfv[j], acc[i][j], 0, 0, 0);
        }
    }

    // epilogue: C row = quad*4 + r, col = lane&15 (HW-verified R4)
#pragma unroll
    for (int i = 0; i < 4; i++) {
        const int rb = m0 + wm + i * 16 + quad * 4;
#pragma unroll
        for (int j = 0; j < 4; j++) {
            const int col = n0 + wn + j * 16 + l15;
            const float bias_v = bias[col];
            if (mode == 2) {
                // V^T direct store: 4 consecutive s at fixed (h,d) -> packed b64
                const int b = rb >> 11, s = rb & 2047;
                const int h = col >> 6, d = col & 63;
                uint2 pk;
                pk.x = pk2(acc[i][j][0] + bias_v, acc[i][j][1] + bias_v);
                pk.y = pk2(acc[i][j][2] + bias_v, acc[i][j][3] + bias_v);
                *(uint2*)&dstb[((b * 16 + h) * 64 + d) * 2048 + s] = pk;
            } else {
#pragma unroll
                for (int r = 0; r < 4; r++) {
                    const float v = acc[i][j][r] + bias_v;
                    const int gm = rb + r;
                    if (mode == 0) {
                        const int b = gm >> 11, s = gm & 2047;
                        const int h = col >> 6, d = col & 63;
                        dstb[((b * 16 + h) * 2048 + s) * 64 + d] = f2b(v);
                    } else {
                        dstf[gm * 1024 + col] = v;
                    }
                }
            }
        }
    }
}

// R9: f32 -> bf16 convert prepass (memory-bound, ~150 MB total traffic).
__global__ __launch_bounds__(256)
void convert_x(const float* __restrict__ q_in, const float* __restrict__ k_in,
               const float* __restrict__ v_in, u16* __restrict__ Xb)
{
    const int z = blockIdx.y;
    const float* src = (z == 0) ? q_in : (z == 1) ? k_in : v_in;
    u16* dst = Xb + z * (8 * 1024 * 1024);
    const int i = (blockIdx.x * 256 + threadIdx.x) * 8;
    const float4 lo = *(const float4*)(src + i);
    const float4 hi = *(const float4*)(src + i + 4);
    *(uint4*)(dst + i) = pack8(lo, hi);
}

__global__ __launch_bounds__(256)
void qkv_kernel_f32(const float* __restrict__ q_in, const float* __restrict__ k_in,
                    const float* __restrict__ v_in, const u16* __restrict__ WT,
                    const float* __restrict__ bq, const float* __restrict__ bk,
                    const float* __restrict__ bv,
                    u16* __restrict__ Qo, u16* __restrict__ Ko, u16* __restrict__ VTo)
{
    const int z = blockIdx.z;
    const float* X   = (z == 0) ? q_in : (z == 1) ? k_in : v_in;
    const u16* wt    = WT + ((z == 0) ? 2 : (z == 1) ? 1 : 0) * (1024 * 1024);
    const float* bias= (z == 0) ? bq : (z == 1) ? bk : bv;
    u16* dst         = (z == 0) ? Qo : (z == 1) ? Ko : VTo;
    gemm128<true>(X, wt, bias, dst, nullptr, (z == 2) ? 2 : 0,
                  blockIdx.y * 128, blockIdx.x * 128);
}

// R9: all-async16 qkv reading pre-converted bf16 X.
// R13: T1 bijective XCD swizzle (512 blocks per z, 512%8==0): 64 consecutive
// work-ids per XCD -> the 8 N-blocks sharing an A-panel live on ONE XCD's L2.
__global__ __launch_bounds__(256)
void qkv_kernel_b16(const u16* __restrict__ Xb, const u16* __restrict__ WT,
                    const float* __restrict__ bq, const float* __restrict__ bk,
                    const float* __restrict__ bv,
                    u16* __restrict__ Qo, u16* __restrict__ Ko, u16* __restrict__ VTo)
{
    const int z = blockIdx.z;
    const u16* X     = Xb + z * (8 * 1024 * 1024);
    const u16* wt    = WT + ((z == 0) ? 2 : (z == 1) ? 1 : 0) * (1024 * 1024);
    const float* bias= (z == 0) ? bq : (z == 1) ? bk : bv;
    u16* dst         = (z == 0) ? Qo : (z == 1) ? Ko : VTo;
    const int s = blockIdx.y * 8 + blockIdx.x;        // dispatch slot 0..511
    const int o = (s & 7) * 64 + (s >> 3);            // XCD-chunked work id
    gemm128<false>(X, wt, bias, dst, nullptr, (z == 2) ? 2 : 0,
                   (o >> 3) * 128, (o & 7) * 128);
}

__global__ __launch_bounds__(256)
void oproj_kernel(const u16* __restrict__ AO, const u16* __restrict__ WT,
                  const float* __restrict__ bo, float* __restrict__ out)
{
    const int s = blockIdx.y * 8 + blockIdx.x;
    const int o = (s & 7) * 64 + (s >> 3);
    gemm128<false>(AO, WT + 3 * 1024 * 1024, bo, nullptr, out, 1,
                   (o >> 3) * 128, (o & 7) * 128);
}

// ---------------- weight transpose+cvt: W[1024 k][1024 n] f32 -> WT[n][k] bf16 ----
__global__ void transpose_w(const float* __restrict__ Wv, const float* __restrict__ Wk,
                            const float* __restrict__ Wq, const float* __restrict__ Wo,
                            u16* __restrict__ WT)
{
    __shared__ u16 tile[64][65];
    const int z = blockIdx.z;
    const float* W = (z == 0) ? Wv : (z == 1) ? Wk : (z == 2) ? Wq : Wo;
    u16* dst = WT + z * 1024 * 1024;
    const int r0 = blockIdx.y * 64, c0 = blockIdx.x * 64;
    const int col = threadIdx.x & 63, rb = threadIdx.x >> 6;
#pragma unroll
    for (int r = rb; r < 64; r += 4) tile[r][col] = f2b(W[(r0 + r) * 1024 + c0 + col]);
    __syncthreads();
#pragma unroll
    for (int r = rb; r < 64; r += 4) dst[(c0 + r) * 1024 + r0 + col] = tile[col][r];
}

// ---------------- flash attention (transposed): Tq=64/block, Tk=128 KV tiles -------
// S^T = K·Q^T -> per-lane online softmax (lane owns one q-row via l15).
// O^T = V^T·P^T (+ ones-row slice accumulating l).
// R11: defer-max THR=8, ones-row l. R12: 2-barrier K-prefetch schedule.
// R13 (attn is LDS~75% + VALU~64% dual-bound; cut VALU + 2 LDS-pipe ops):
//  - persistent cinit (0 normally, -m_st post-breach) as MFMA C-in: kills the
//    32 per-iter v_movs of s-init.
//  - cross-lane max shuffles moved INSIDE the breach branch (__any needs only
//    the per-lane max): -2 ds_swizzle + ~50cy VALU per iter on the common path.
__global__ __launch_bounds__(256, 3)
void attn_kernel(const u16* __restrict__ Q, const u16* __restrict__ K,
                 const u16* __restrict__ VT, u16* __restrict__ AO)
{
    __shared__ __align__(16) u16 Ks[128 * 64];    // K tile (swizzle r&7)
    __shared__ __align__(16) u16 Ps[64 * 128];    // P^T (swizzle r&15, wave-private rows)
    __shared__ __align__(16) u16 Vts[80 * 128];   // rows 0..63: V^T (swizzle r&15);
                                                  // row 64: ones, 65..79: zeros

    const int t    = threadIdx.x;
    const int lane = t & 63;
    const int wave = t >> 6;
    const int quad = lane >> 4;
    const int l15  = lane & 15;
    const int bh = blockIdx.y;
    const int qt = blockIdx.x;

    const u16* Qg = Q + (bh * 2048 + qt * 64) * 64;
    const u16* Kg = K + bh * 2048 * 64;
    const u16* Vg = VT + bh * 64 * 2048;

    // hoisted staging maps: running global src pointers + fixed LDS dests
    const u16* kgp[4];
    const u16* vgp[4];
    u16* kld[4];
    u16* vld[4];
#pragma unroll
    for (int c = 0; c < 4; c++) {
        const int ci = c * 256 + t;
        const int krr = ci >> 3, klb = (ci & 7)  ^ (krr & 7);
        const int vrr = ci >> 4, vlb = (ci & 15) ^ (vrr & 15);
        kgp[c] = Kg + krr * 64 + klb * 8;      // += 128*64 per issue
        vgp[c] = Vg + vrr * 2048 + vlb * 8;    // += 128 per issue
        kld[c] = &Ks[ci * 8];
        vld[c] = &Vts[ci * 8];
    }

    // prologue: issue K[0] now; it lands under Q-load + ones-init below
#pragma unroll
    for (int c = 0; c < 4; c++) {
        async16(kgp[c], kld[c]);
        kgp[c] += 128 * 64;
    }

    // ones/zeros rows for the row-sum MFMA slice (written once; staging never
    // touches rows >= 64)
    {
        const int idx = t * 8;                 // 2048 u16 over 256 threads
        const int row = 64 + (idx >> 7);
        const u16 one = 0x3F80;                // bf16 1.0
        u16 vals[8];
#pragma unroll
        for (int i = 0; i < 8; i++) vals[i] = (row == 64) ? one : (u16)0;
        *(uint4*)&Vts[64 * 128 + idx] = *(uint4*)vals;
    }

    // Q fragments in registers (fold 0.125*log2e -> exp2 domain)
    bf16x8 bqr[2];
    {
        const u16* qrow = Qg + (wave * 16 + l15) * 64 + quad * 8;
#pragma unroll
        for (int c = 0; c < 2; c++) {
            uint4 dv = *(const uint4*)(qrow + c * 32);
            u16 tmp[8];
            *(uint4*)tmp = dv;
            float f[8];
#pragma unroll
            for (int i = 0; i < 8; i++) {
                union { float f; uint32_t u; } x; x.u = ((uint32_t)tmp[i]) << 16;
                f[i] = x.f * 0.18033688f;   // 0.125 * log2e
            }
            uint4 pk;
            pk.x = pk2(f[0], f[1]); pk.y = pk2(f[2], f[3]);
            pk.z = pk2(f[4], f[5]); pk.w = pk2(f[6], f[7]);
            bqr[c] = *(bf16x8*)&pk;
        }
    }

    f32x4 o[5];                                // o[4] = online l (ones-row slice)
#pragma unroll
    for (int dj = 0; dj < 5; dj++)
#pragma unroll
        for (int r = 0; r < 4; r++) o[dj][r] = 0.0f;
    float m_st = 0.0f;                         // T13: defer-max, start at 0
    f32x4 cinit;                               // R13: persistent C-in (= -m_st)
#pragma unroll
    for (int r = 0; r < 4; r++) cinit[r] = 0.0f;

    // QK^T A-frag LDS offsets (u16 units): [kk/32][n]
    int ak_off[2][8];
#pragma unroll
    for (int ki = 0; ki < 2; ki++)
#pragma unroll
        for (int n = 0; n < 8; n++)
            ak_off[ki][n] = (n * 16 + l15) * 64 + (((ki * 4) + quad) ^ (l15 & 7)) * 8;
    // PV offsets: av [ks][dj] (dj 0..4), bp [ks]; P-write offsets pw [n]
    int av_off[4][5], bp_off[4], pw_off[8];
#pragma unroll
    for (int ks = 0; ks < 4; ks++) {
        bp_off[ks] = (wave * 16 + l15) * 128 + ((ks * 4 + quad) ^ l15) * 8;
#pragma unroll
        for (int dj = 0; dj < 5; dj++)
            av_off[ks][dj] = (dj * 16 + l15) * 128 + ((ks * 4 + quad) ^ l15) * 8;
    }
#pragma unroll
    for (int n = 0; n < 8; n++)
        pw_off[n] = (wave * 16 + l15) * 128 + ((2 * n + (quad >> 1)) ^ l15) * 8
                    + (quad & 1) * 4;

    for (int kv = 0; kv < 16; kv++) {
        // (a): drains K[t] (issued a full iter ago -> landed); syncs prev PV reads
        //      of Vts before V[t] staging writes; makes Ks[t] visible to all waves
        __syncthreads();
#pragma unroll
        for (int c = 0; c < 4; c++) {      // V[t]: flies under QK^T
            async16(vgp[c], vld[c]);
            vgp[c] += 128;
        }

        // S^T = K·Q^T, C-in = cinit (0, or -m_st post-breach): zero per-iter movs
        f32x4 s[8];
#pragma unroll
        for (int n = 0; n < 8; n++)
            s[n] = __builtin_amdgcn_mfma_f32_16x16x32_bf16(
                *(const bf16x8*)&Ks[ak_off[0][n]], bqr[0], cinit, 0, 0, 0);
#pragma unroll
        for (int n = 0; n < 8; n++)
            s[n] = __builtin_amdgcn_mfma_f32_16x16x32_bf16(
                *(const bf16x8*)&Ks[ak_off[1][n]], bqr[1], s[n], 0, 0, 0);

        // (c): all waves' Ks[t] reads done (K[t+1] may overwrite after this);
        //      drains V[t] (latency mostly absorbed under QK^T) -> Vts visible
        __syncthreads();
        if (kv < 15) {
#pragma unroll
            for (int c = 0; c < 4; c++) {  // K[t+1]: flies across softmax+PV
                async16(kgp[c], kld[c]);
                kgp[c] += 128 * 64;
            }
        }

        // per-lane max only; cross-lane shuffles deferred into the breach branch
        float mxn[8];
#pragma unroll
        for (int n = 0; n < 8; n++)
            mxn[n] = fmaxf(fmaxf(s[n][0], s[n][1]), fmaxf(s[n][2], s[n][3]));
        float mx = fmaxf(fmaxf(fmaxf(mxn[0], mxn[1]), fmaxf(mxn[2], mxn[3])),
                         fmaxf(fmaxf(mxn[4], mxn[5]), fmaxf(mxn[6], mxn[7])));
        if (__any(mx > 8.0f)) {                // rare: tile max grew past THR
            mx = fmaxf(mx, __shfl_xor(mx, 16));
            mx = fmaxf(mx, __shfl_xor(mx, 32));    // per-column max
            const float dm = fmaxf(mx, 0.0f);
            const float alpha = exp2f(-dm);
#pragma unroll
            for (int n = 0; n < 8; n++)
#pragma unroll
                for (int r = 0; r < 4; r++) s[n][r] -= dm;
            m_st += dm;
#pragma unroll
            for (int r = 0; r < 4; r++) cinit[r] = -m_st;
#pragma unroll
            for (int dj = 0; dj < 5; dj++)
#pragma unroll
                for (int r = 0; r < 4; r++) o[dj][r] *= alpha;
        }

        // P = exp2(s) -> packed bf16 -> swizzled Ps (wave-private rows)
#pragma unroll
        for (int n = 0; n < 8; n++) {
            uint2 pk;
            pk.x = pk2(exp2f(s[n][0]), exp2f(s[n][1]));
            pk.y = pk2(exp2f(s[n][2]), exp2f(s[n][3]));
            *(uint2*)&Ps[pw_off[n]] = pk;
        }
        asm volatile("s_waitcnt lgkmcnt(0)" ::: "memory");  // wave-private RAW fence

        // O^T += V^T·P^T  (dj=4 is the ones-row slice: accumulates l into o[4])
#pragma unroll
        for (int ks = 0; ks < 4; ks++) {
            const bf16x8 bp = *(const bf16x8*)&Ps[bp_off[ks]];
#pragma unroll
            for (int dj = 0; dj < 5; dj++) {
                const bf16x8 av = *(const bf16x8*)&Vts[av_off[ks][dj]];
                o[dj] = __builtin_amdgcn_mfma_f32_16x16x32_bf16(av, bp, o[dj], 0, 0, 0);
            }
        }
    }

    // epilogue: l for column q=l15 lives in lane (quad 0, l15), reg 0 of o[4]
    const float lsum = __shfl(o[4][0], l15);
    const int b = bh >> 4, h = bh & 15;
    const int sq = qt * 64 + wave * 16 + l15;
    const float inv = 1.0f / lsum;
#pragma unroll
    for (int dj = 0; dj < 4; dj++) {
        uint2 pk;
        pk.x = pk2(o[dj][0] * inv, o[dj][1] * inv);
        pk.y = pk2(o[dj][2] * inv, o[dj][3] * inv);
        *(uint2*)&AO[(b * 2048 + sq) * 1024 + h * 64 + dj * 16 + quad * 4] = pk;
    }
}

extern "C" void kernel_launch(void* const* d_in, const int* in_sizes, int n_in,
                              void* d_out, int out_size, void* d_ws, size_t ws_size,
                              hipStream_t stream)
{
    (void)in_sizes; (void)n_in; (void)out_size;
    const float* value = (const float*)d_in[0];
    const float* key_  = (const float*)d_in[1];
    const float* query = (const float*)d_in[2];
    const float* Wv = (const float*)d_in[3];
    const float* bv = (const float*)d_in[4];
    const float* Wk = (const float*)d_in[5];
    const float* bk = (const float*)d_in[6];
    const float* Wq = (const float*)d_in[7];
    const float* bq = (const float*)d_in[8];
    const float* Wo = (const float*)d_in[9];
    const float* bo = (const float*)d_in[10];

    u16* ws = (u16*)d_ws;
    u16* WT = ws;                          // 4 x 1M bf16 (order: v,k,q,o)
    u16* Q  = ws + 4 * 1024 * 1024;        // 8M bf16 [B,H,S,D]
    u16* K  = Q + 8 * 1024 * 1024;         // 8M [B,H,S,D]
    u16* VT = K + 8 * 1024 * 1024;         // 8M [B,H,D,S] (written directly by qkv)
    u16* AO = VT + 8 * 1024 * 1024;        // 8M [B*S, E]   (72 MB so far)
    u16* Xb = AO + 8 * 1024 * 1024;        // 3 x 8M bf16 converted inputs (q,k,v)
    const size_t need = (size_t)(4 + 8 + 8 + 8 + 8 + 24) * 1024 * 1024 * sizeof(u16);

    transpose_w<<<dim3(16, 16, 4), dim3(256), 0, stream>>>(Wv, Wk, Wq, Wo, WT);
    if (ws_size >= need) {
        convert_x<<<dim3(4096, 3), dim3(256), 0, stream>>>(query, key_, value, Xb);
        qkv_kernel_b16<<<dim3(8, 64, 3), dim3(256), 0, stream>>>(Xb, WT, bq, bk, bv,
                                                                 Q, K, VT);
    } else {
        qkv_kernel_f32<<<dim3(8, 64, 3), dim3(256), 0, stream>>>(query, key_, value,
                                                                 WT, bq, bk, bv,
                                                                 Q, K, VT);
    }
    attn_kernel<<<dim3(32, 64), dim3(256), 0, stream>>>(Q, K, VT, AO);
    oproj_kernel<<<dim3(8, 64, 1), dim3(256), 0, stream>>>(AO, WT, bo, (float*)d_out);
}

// Round 9
// 360.558 us; speedup vs baseline: 1.1043x; 1.0544x over previous
//
#include <hip/hip_runtime.h>
#include <hip/hip_bf16.h>
#include <stdint.h>

typedef unsigned short u16;
typedef __bf16 bf16_t;
typedef bf16_t bf16x8 __attribute__((ext_vector_type(8)));
typedef float f32x4 __attribute__((ext_vector_type(4)));

__device__ __forceinline__ u16 f2b(float f) {
    union { float f; uint32_t i; } v; v.f = f;
    uint32_t r = v.i + 0x7FFFu + ((v.i >> 16) & 1u);
    return (u16)(r >> 16);
}
__device__ __forceinline__ uint32_t pk2(float a, float b) {
    __hip_bfloat162 h = __float22bfloat162_rn(float2{a, b});
    return *(const uint32_t*)&h;
}
__device__ __forceinline__ uint4 pack8(float4 lo, float4 hi) {
    uint4 r;
    r.x = pk2(lo.x, lo.y); r.y = pk2(lo.z, lo.w);
    r.z = pk2(hi.x, hi.y); r.w = pk2(hi.z, hi.w);
    return r;
}
// async global->LDS DMA, 16B per lane (m97 idiom: LDS dst linear in lane)
__device__ __forceinline__ void async16(const u16* g, u16* l) {
    __builtin_amdgcn_global_load_lds(
        (const __attribute__((address_space(1))) uint32_t*)g,
        (__attribute__((address_space(3))) uint32_t*)l,
        16, 0, 0);
}

// ---------------- GEMM core: C[M,N] = X[M,1024] @ W[1024,N] + bias ----------------
// WT = W^T bf16 [N][K]. 128x128 tile, BK=64, 2x2 wave quadrants, 4x4 16x16x32 frags.
// LDS tiles 128x64, unpadded, XOR-swizzled.
// R14: DOUBLE-BUFFERED 1-barrier pipeline (T3 minimum-2-phase): issue loads for
// kt+64 into buf^1 right after the barrier, compute buf, ONE __syncthreads. The
// vmcnt(0) drain at the barrier covers loads that had the whole compute phase
// (~500-900cy) to land -> staging latency hidden without counted waits.
// Hazards: loads->buf^1 write a buffer whose reads completed before the PREVIOUS
// barrier; compute reads data drained by the previous barrier. Both ordered.
// mode 0: bf16 scatter [B,H,S,D]; mode 1: f32 row-major; mode 2: bf16 V^T [BH,64,2048]
template<bool XF32>
__device__ __forceinline__ void gemm128(const void* __restrict__ Xv,
                                        const u16* __restrict__ WT,
                                        const float* __restrict__ bias,
                                        u16* __restrict__ dstb,
                                        float* __restrict__ dstf, int mode,
                                        int m0, int n0)
{
    __shared__ __align__(16) u16 As[2][128 * 64];
    __shared__ __align__(16) u16 Bs[2][128 * 64];
    const int t    = threadIdx.x;
    const int lane = t & 63;
    const int quad = lane >> 4;
    const int l15  = lane & 15;
    const int wave = t >> 6;
    const int wm = (wave >> 1) * 64;
    const int wn = (wave & 1) * 64;

    f32x4 acc[4][4];
#pragma unroll
    for (int i = 0; i < 4; i++)
#pragma unroll
        for (int j = 0; j < 4; j++)
#pragma unroll
            for (int r = 0; r < 4; r++) acc[i][j][r] = 0.0f;

    // staging chunk map: ci = c*256+t; row r=ci>>3, physical block pb=ci&7,
    // logical (global) block lb = pb ^ (r&7)
    int rr[4], lb[4];
#pragma unroll
    for (int c = 0; c < 4; c++) {
        const int ci = c * 256 + t;
        rr[c] = ci >> 3;
        lb[c] = (ci & 7) ^ (rr[c] & 7);
    }

#define STAGE_TILE(buf, kt)                                                         \
    do {                                                                            \
        _Pragma("unroll")                                                           \
        for (int c = 0; c < 4; c++)                                                 \
            async16(WT + (n0 + rr[c]) * 1024 + (kt) + lb[c] * 8,                    \
                    &Bs[buf][(c * 256 + t) * 8]);                                   \
        if (XF32) {                                                                 \
            _Pragma("unroll")                                                       \
            for (int c = 0; c < 4; c++) {                                           \
                const float* g = (const float*)Xv + (m0 + rr[c]) * 1024 + (kt)      \
                                 + lb[c] * 8;                                       \
                const float4 lo = *(const float4*)g;                                \
                const float4 hi = *(const float4*)(g + 4);                          \
                *(uint4*)&As[buf][(c * 256 + t) * 8] = pack8(lo, hi);               \
            }                                                                       \
        } else {                                                                    \
            _Pragma("unroll")                                                       \
            for (int c = 0; c < 4; c++)                                             \
                async16((const u16*)Xv + (m0 + rr[c]) * 1024 + (kt) + lb[c] * 8,    \
                        &As[buf][(c * 256 + t) * 8]);                               \
        }                                                                           \
    } while (0)

    // prologue: stage kt=0 into buf 0, drain
    STAGE_TILE(0, 0);
    __syncthreads();

    int cur = 0;
    for (int kt = 0; kt < 1024; kt += 64) {
        if (kt < 960)                       // stage kt+64: flies under compute
            STAGE_TILE(cur ^ 1, kt + 64);

#pragma unroll
        for (int kk = 0; kk < 64; kk += 32) {
            bf16x8 af[4], bfv[4];
#pragma unroll
            for (int i = 0; i < 4; i++) {
                const int ra = wm + i * 16 + l15;
                const int rb2 = wn + i * 16 + l15;
                af[i]  = *(const bf16x8*)&As[cur][ra * 64 + (((kk >> 3) + quad) ^ (l15 & 7)) * 8];
                bfv[i] = *(const bf16x8*)&Bs[cur][rb2 * 64 + (((kk >> 3) + quad) ^ (l15 & 7)) * 8];
            }
#pragma unroll
            for (int i = 0; i < 4; i++)
#pragma unroll
                for (int j = 0; j < 4; j++)
                    acc[i][j] = __builtin_amdgcn_mfma_f32_16x16x32_bf16(af[i], bfv[j], acc[i][j], 0, 0, 0);
        }

        __syncthreads();                    // drains kt+64 loads (landed under compute)
        cur ^= 1;
    }
#undef STAGE_TILE

    // epilogue: C row = quad*4 + r, col = lane&15 (HW-verified R4)
#pragma unroll
    for (int i = 0; i < 4; i++) {
        const int rb = m0 + wm + i * 16 + quad * 4;
#pragma unroll
        for (int j = 0; j < 4; j++) {
            const int col = n0 + wn + j * 16 + l15;
            const float bias_v = bias[col];
            if (mode == 2) {
                // V^T direct store: 4 consecutive s at fixed (h,d) -> packed b64
                const int b = rb >> 11, s = rb & 2047;
                const int h = col >> 6, d = col & 63;
                uint2 pk;
                pk.x = pk2(acc[i][j][0] + bias_v, acc[i][j][1] + bias_v);
                pk.y = pk2(acc[i][j][2] + bias_v, acc[i][j][3] + bias_v);
                *(uint2*)&dstb[((b * 16 + h) * 64 + d) * 2048 + s] = pk;
            } else {
#pragma unroll
                for (int r = 0; r < 4; r++) {
                    const float v = acc[i][j][r] + bias_v;
                    const int gm = rb + r;
                    if (mode == 0) {
                        const int b = gm >> 11, s = gm & 2047;
                        const int h = col >> 6, d = col & 63;
                        dstb[((b * 16 + h) * 2048 + s) * 64 + d] = f2b(v);
                    } else {
                        dstf[gm * 1024 + col] = v;
                    }
                }
            }
        }
    }
}

// R9: f32 -> bf16 convert prepass (memory-bound, ~150 MB total traffic).
__global__ __launch_bounds__(256)
void convert_x(const float* __restrict__ q_in, const float* __restrict__ k_in,
               const float* __restrict__ v_in, u16* __restrict__ Xb)
{
    const int z = blockIdx.y;
    const float* src = (z == 0) ? q_in : (z == 1) ? k_in : v_in;
    u16* dst = Xb + z * (8 * 1024 * 1024);
    const int i = (blockIdx.x * 256 + threadIdx.x) * 8;
    const float4 lo = *(const float4*)(src + i);
    const float4 hi = *(const float4*)(src + i + 4);
    *(uint4*)(dst + i) = pack8(lo, hi);
}

__global__ __launch_bounds__(256)
void qkv_kernel_f32(const float* __restrict__ q_in, const float* __restrict__ k_in,
                    const float* __restrict__ v_in, const u16* __restrict__ WT,
                    const float* __restrict__ bq, const float* __restrict__ bk,
                    const float* __restrict__ bv,
                    u16* __restrict__ Qo, u16* __restrict__ Ko, u16* __restrict__ VTo)
{
    const int z = blockIdx.z;
    const float* X   = (z == 0) ? q_in : (z == 1) ? k_in : v_in;
    const u16* wt    = WT + ((z == 0) ? 2 : (z == 1) ? 1 : 0) * (1024 * 1024);
    const float* bias= (z == 0) ? bq : (z == 1) ? bk : bv;
    u16* dst         = (z == 0) ? Qo : (z == 1) ? Ko : VTo;
    gemm128<true>(X, wt, bias, dst, nullptr, (z == 2) ? 2 : 0,
                  blockIdx.y * 128, blockIdx.x * 128);
}

// R9: all-async16 qkv reading pre-converted bf16 X.
// R13: T1 bijective XCD swizzle (512 blocks per z, 512%8==0): 64 consecutive
// work-ids per XCD -> the 8 N-blocks sharing an A-panel live on ONE XCD's L2.
__global__ __launch_bounds__(256)
void qkv_kernel_b16(const u16* __restrict__ Xb, const u16* __restrict__ WT,
                    const float* __restrict__ bq, const float* __restrict__ bk,
                    const float* __restrict__ bv,
                    u16* __restrict__ Qo, u16* __restrict__ Ko, u16* __restrict__ VTo)
{
    const int z = blockIdx.z;
    const u16* X     = Xb + z * (8 * 1024 * 1024);
    const u16* wt    = WT + ((z == 0) ? 2 : (z == 1) ? 1 : 0) * (1024 * 1024);
    const float* bias= (z == 0) ? bq : (z == 1) ? bk : bv;
    u16* dst         = (z == 0) ? Qo : (z == 1) ? Ko : VTo;
    const int s = blockIdx.y * 8 + blockIdx.x;        // dispatch slot 0..511
    const int o = (s & 7) * 64 + (s >> 3);            // XCD-chunked work id
    gemm128<false>(X, wt, bias, dst, nullptr, (z == 2) ? 2 : 0,
                   (o >> 3) * 128, (o & 7) * 128);
}

__global__ __launch_bounds__(256)
void oproj_kernel(const u16* __restrict__ AO, const u16* __restrict__ WT,
                  const float* __restrict__ bo, float* __restrict__ out)
{
    const int s = blockIdx.y * 8 + blockIdx.x;
    const int o = (s & 7) * 64 + (s >> 3);
    gemm128<false>(AO, WT + 3 * 1024 * 1024, bo, nullptr, out, 1,
                   (o >> 3) * 128, (o & 7) * 128);
}

// ---------------- weight transpose+cvt: W[1024 k][1024 n] f32 -> WT[n][k] bf16 ----
__global__ void transpose_w(const float* __restrict__ Wv, const float* __restrict__ Wk,
                            const float* __restrict__ Wq, const float* __restrict__ Wo,
                            u16* __restrict__ WT)
{
    __shared__ u16 tile[64][65];
    const int z = blockIdx.z;
    const float* W = (z == 0) ? Wv : (z == 1) ? Wk : (z == 2) ? Wq : Wo;
    u16* dst = WT + z * 1024 * 1024;
    const int r0 = blockIdx.y * 64, c0 = blockIdx.x * 64;
    const int col = threadIdx.x & 63, rb = threadIdx.x >> 6;
#pragma unroll
    for (int r = rb; r < 64; r += 4) tile[r][col] = f2b(W[(r0 + r) * 1024 + c0 + col]);
    __syncthreads();
#pragma unroll
    for (int r = rb; r < 64; r += 4) dst[(c0 + r) * 1024 + r0 + col] = tile[col][r];
}

// ---------------- flash attention (transposed): Tq=64/block, Tk=128 KV tiles -------
// S^T = K·Q^T -> per-lane online softmax (lane owns one q-row via l15).
// O^T = V^T·P^T (+ ones-slice accumulating l).
// R11: defer-max THR=8, ones-row l. R12: 2-barrier K-prefetch schedule.
// R13: persistent cinit; shuffles inside breach branch.
// R14: ones A-frag is CONSTANT per lane (l15==0 ? 1.0 : 0) -> compute in regs,
//      delete Vts rows 64..79 + init pass. -4 b128 LDS reads/wave/iter and
//      LDS 53248 -> 49152 (3 blocks/CU with comfortable margin).
__global__ __launch_bounds__(256, 3)
void attn_kernel(const u16* __restrict__ Q, const u16* __restrict__ K,
                 const u16* __restrict__ VT, u16* __restrict__ AO)
{
    __shared__ __align__(16) u16 Ks[128 * 64];    // K tile (swizzle r&7)
    __shared__ __align__(16) u16 Ps[64 * 128];    // P^T (swizzle r&15, wave-private rows)
    __shared__ __align__(16) u16 Vts[64 * 128];   // V^T (swizzle r&15)

    const int t    = threadIdx.x;
    const int lane = t & 63;
    const int wave = t >> 6;
    const int quad = lane >> 4;
    const int l15  = lane & 15;
    const int bh = blockIdx.y;
    const int qt = blockIdx.x;

    const u16* Qg = Q + (bh * 2048 + qt * 64) * 64;
    const u16* Kg = K + bh * 2048 * 64;
    const u16* Vg = VT + bh * 64 * 2048;

    // hoisted staging maps: running global src pointers + fixed LDS dests
    const u16* kgp[4];
    const u16* vgp[4];
    u16* kld[4];
    u16* vld[4];
#pragma unroll
    for (int c = 0; c < 4; c++) {
        const int ci = c * 256 + t;
        const int krr = ci >> 3, klb = (ci & 7)  ^ (krr & 7);
        const int vrr = ci >> 4, vlb = (ci & 15) ^ (vrr & 15);
        kgp[c] = Kg + krr * 64 + klb * 8;      // += 128*64 per issue
        vgp[c] = Vg + vrr * 2048 + vlb * 8;    // += 128 per issue
        kld[c] = &Ks[ci * 8];
        vld[c] = &Vts[ci * 8];
    }

    // prologue: issue K[0] now; it lands under Q-load below
#pragma unroll
    for (int c = 0; c < 4; c++) {
        async16(kgp[c], kld[c]);
        kgp[c] += 128 * 64;
    }

    // R14: constant ones A-frag for the l-accumulating PV slice
    bf16x8 aones;
    {
        const u16 one = (l15 == 0) ? (u16)0x3F80 : (u16)0;
        u16 vals[8];
#pragma unroll
        for (int i = 0; i < 8; i++) vals[i] = one;
        aones = *(bf16x8*)vals;
    }

    // Q fragments in registers (fold 0.125*log2e -> exp2 domain)
    bf16x8 bqr[2];
    {
        const u16* qrow = Qg + (wave * 16 + l15) * 64 + quad * 8;
#pragma unroll
        for (int c = 0; c < 2; c++) {
            uint4 dv = *(const uint4*)(qrow + c * 32);
            u16 tmp[8];
            *(uint4*)tmp = dv;
            float f[8];
#pragma unroll
            for (int i = 0; i < 8; i++) {
                union { float f; uint32_t u; } x; x.u = ((uint32_t)tmp[i]) << 16;
                f[i] = x.f * 0.18033688f;   // 0.125 * log2e
            }
            uint4 pk;
            pk.x = pk2(f[0], f[1]); pk.y = pk2(f[2], f[3]);
            pk.z = pk2(f[4], f[5]); pk.w = pk2(f[6], f[7]);
            bqr[c] = *(bf16x8*)&pk;
        }
    }

    f32x4 o[5];                                // o[4] = online l (ones slice)
#pragma unroll
    for (int dj = 0; dj < 5; dj++)
#pragma unroll
        for (int r = 0; r < 4; r++) o[dj][r] = 0.0f;
    float m_st = 0.0f;                         // T13: defer-max, start at 0
    f32x4 cinit;                               // R13: persistent C-in (= -m_st)
#pragma unroll
    for (int r = 0; r < 4; r++) cinit[r] = 0.0f;

    // QK^T A-frag LDS offsets (u16 units): [kk/32][n]
    int ak_off[2][8];
#pragma unroll
    for (int ki = 0; ki < 2; ki++)
#pragma unroll
        for (int n = 0; n < 8; n++)
            ak_off[ki][n] = (n * 16 + l15) * 64 + (((ki * 4) + quad) ^ (l15 & 7)) * 8;
    // PV offsets: av [ks][dj] (dj 0..3), bp [ks]; P-write offsets pw [n]
    int av_off[4][4], bp_off[4], pw_off[8];
#pragma unroll
    for (int ks = 0; ks < 4; ks++) {
        bp_off[ks] = (wave * 16 + l15) * 128 + ((ks * 4 + quad) ^ l15) * 8;
#pragma unroll
        for (int dj = 0; dj < 4; dj++)
            av_off[ks][dj] = (dj * 16 + l15) * 128 + ((ks * 4 + quad) ^ l15) * 8;
    }
#pragma unroll
    for (int n = 0; n < 8; n++)
        pw_off[n] = (wave * 16 + l15) * 128 + ((2 * n + (quad >> 1)) ^ l15) * 8
                    + (quad & 1) * 4;

    for (int kv = 0; kv < 16; kv++) {
        // (a): drains K[t] (issued a full iter ago -> landed); syncs prev PV reads
        //      of Vts before V[t] staging writes; makes Ks[t] visible to all waves
        __syncthreads();
#pragma unroll
        for (int c = 0; c < 4; c++) {      // V[t]: flies under QK^T
            async16(vgp[c], vld[c]);
            vgp[c] += 128;
        }

        // S^T = K·Q^T, C-in = cinit (0, or -m_st post-breach): zero per-iter movs
        f32x4 s[8];
#pragma unroll
        for (int n = 0; n < 8; n++)
            s[n] = __builtin_amdgcn_mfma_f32_16x16x32_bf16(
                *(const bf16x8*)&Ks[ak_off[0][n]], bqr[0], cinit, 0, 0, 0);
#pragma unroll
        for (int n = 0; n < 8; n++)
            s[n] = __builtin_amdgcn_mfma_f32_16x16x32_bf16(
                *(const bf16x8*)&Ks[ak_off[1][n]], bqr[1], s[n], 0, 0, 0);

        // (c): all waves' Ks[t] reads done (K[t+1] may overwrite after this);
        //      drains V[t] (latency mostly absorbed under QK^T) -> Vts visible
        __syncthreads();
        if (kv < 15) {
#pragma unroll
            for (int c = 0; c < 4; c++) {  // K[t+1]: flies across softmax+PV
                async16(kgp[c], kld[c]);
                kgp[c] += 128 * 64;
            }
        }

        // per-lane max only; cross-lane shuffles deferred into the breach branch
        float mxn[8];
#pragma unroll
        for (int n = 0; n < 8; n++)
            mxn[n] = fmaxf(fmaxf(s[n][0], s[n][1]), fmaxf(s[n][2], s[n][3]));
        float mx = fmaxf(fmaxf(fmaxf(mxn[0], mxn[1]), fmaxf(mxn[2], mxn[3])),
                         fmaxf(fmaxf(mxn[4], mxn[5]), fmaxf(mxn[6], mxn[7])));
        if (__any(mx > 8.0f)) {                // rare: tile max grew past THR
            mx = fmaxf(mx, __shfl_xor(mx, 16));
            mx = fmaxf(mx, __shfl_xor(mx, 32));    // per-column max
            const float dm = fmaxf(mx, 0.0f);
            const float alpha = exp2f(-dm);
#pragma unroll
            for (int n = 0; n < 8; n++)
#pragma unroll
                for (int r = 0; r < 4; r++) s[n][r] -= dm;
            m_st += dm;
#pragma unroll
            for (int r = 0; r < 4; r++) cinit[r] = -m_st;
#pragma unroll
            for (int dj = 0; dj < 5; dj++)
#pragma unroll
                for (int r = 0; r < 4; r++) o[dj][r] *= alpha;
        }

        // P = exp2(s) -> packed bf16 -> swizzled Ps (wave-private rows)
#pragma unroll
        for (int n = 0; n < 8; n++) {
            uint2 pk;
            pk.x = pk2(exp2f(s[n][0]), exp2f(s[n][1]));
            pk.y = pk2(exp2f(s[n][2]), exp2f(s[n][3]));
            *(uint2*)&Ps[pw_off[n]] = pk;
        }
        asm volatile("s_waitcnt lgkmcnt(0)" ::: "memory");  // wave-private RAW fence

        // O^T += V^T·P^T  (dj=4: ones slice from REGISTERS accumulates l)
#pragma unroll
        for (int ks = 0; ks < 4; ks++) {
            const bf16x8 bp = *(const bf16x8*)&Ps[bp_off[ks]];
#pragma unroll
            for (int dj = 0; dj < 4; dj++) {
                const bf16x8 av = *(const bf16x8*)&Vts[av_off[ks][dj]];
                o[dj] = __builtin_amdgcn_mfma_f32_16x16x32_bf16(av, bp, o[dj], 0, 0, 0);
            }
            o[4] = __builtin_amdgcn_mfma_f32_16x16x32_bf16(aones, bp, o[4], 0, 0, 0);
        }
    }

    // epilogue: l for column q=l15 lives in lane (quad 0, l15), reg 0 of o[4]
    const float lsum = __shfl(o[4][0], l15);
    const int b = bh >> 4, h = bh & 15;
    const int sq = qt * 64 + wave * 16 + l15;
    const float inv = 1.0f / lsum;
#pragma unroll
    for (int dj = 0; dj < 4; dj++) {
        uint2 pk;
        pk.x = pk2(o[dj][0] * inv, o[dj][1] * inv);
        pk.y = pk2(o[dj][2] * inv, o[dj][3] * inv);
        *(uint2*)&AO[(b * 2048 + sq) * 1024 + h * 64 + dj * 16 + quad * 4] = pk;
    }
}

extern "C" void kernel_launch(void* const* d_in, const int* in_sizes, int n_in,
                              void* d_out, int out_size, void* d_ws, size_t ws_size,
                              hipStream_t stream)
{
    (void)in_sizes; (void)n_in; (void)out_size;
    const float* value = (const float*)d_in[0];
    const float* key_  = (const float*)d_in[1];
    const float* query = (const float*)d_in[2];
    const float* Wv = (const float*)d_in[3];
    const float* bv = (const float*)d_in[4];
    const float* Wk = (const float*)d_in[5];
    const float* bk = (const float*)d_in[6];
    const float* Wq = (const float*)d_in[7];
    const float* bq = (const float*)d_in[8];
    const float* Wo = (const float*)d_in[9];
    const float* bo = (const float*)d_in[10];

    u16* ws = (u16*)d_ws;
    u16* WT = ws;                          // 4 x 1M bf16 (order: v,k,q,o)
    u16* Q  = ws + 4 * 1024 * 1024;        // 8M bf16 [B,H,S,D]
    u16* K  = Q + 8 * 1024 * 1024;         // 8M [B,H,S,D]
    u16* VT = K + 8 * 1024 * 1024;         // 8M [B,H,D,S] (written directly by qkv)
    u16* AO = VT + 8 * 1024 * 1024;        // 8M [B*S, E]   (72 MB so far)
    u16* Xb = AO + 8 * 1024 * 1024;        // 3 x 8M bf16 converted inputs (q,k,v)
    const size_t need = (size_t)(4 + 8 + 8 + 8 + 8 + 24) * 1024 * 1024 * sizeof(u16);

    transpose_w<<<dim3(16, 16, 4), dim3(256), 0, stream>>>(Wv, Wk, Wq, Wo, WT);
    if (ws_size >= need) {
        convert_x<<<dim3(4096, 3), dim3(256), 0, stream>>>(query, key_, value, Xb);
        qkv_kernel_b16<<<dim3(8, 64, 3), dim3(256), 0, stream>>>(Xb, WT, bq, bk, bv,
                                                                 Q, K, VT);
    } else {
        qkv_kernel_f32<<<dim3(8, 64, 3), dim3(256), 0, stream>>>(query, key_, value,
                                                                 WT, bq, bk, bv,
                                                                 Q, K, VT);
    }
    attn_kernel<<<dim3(32, 64), dim3(256), 0, stream>>>(Q, K, VT, AO);
    oproj_kernel<<<dim3(8, 64, 1), dim3(256), 0, stream>>>(AO, WT, bo, (float*)d_out);
}